// Round 2
// baseline (186.981 us; speedup 1.0000x reference)
//
#include <hip/hip_runtime.h>

#define NGRID 512
#define NV (NGRID * NGRID)          // 262144
#define NB 4
#define NVIEWS 4
#define FEPS 1e-6f
#define TR 2                        // owned rows per block
#define LDS_ROWS (TR + 2)           // + top/bottom halo
#define ROWF (NGRID * 3)            // 1536 packed floats per row
#define LDSF4 (LDS_ROWS * ROWF / 4) // 1536 float4 staging chunks per tile

typedef float fvec4 __attribute__((ext_vector_type(4)));

static constexpr size_t NVF3 = (size_t)NV * 3;                      // 786432
static constexpr size_t VERTS_FLOATS = (size_t)NVIEWS * NB * NVF3;  // 12,582,912
static constexpr size_t LAP_OFF = 2 * VERTS_FLOATS;
static constexpr size_t FLAT_OFF = LAP_OFF + 1;

__device__ __forceinline__ float frcp(float x)  { return __builtin_amdgcn_rcpf(x); }
__device__ __forceinline__ float fsqrt_(float x){ return __builtin_amdgcn_sqrtf(x); }

// ---------------------------------------------------------------------------
__global__ void init_losses(float* __restrict__ out) {
    if (threadIdx.x == 0) {
        out[LAP_OFF] = 0.0f;
        out[FLAT_OFF] = 0.0f;
    }
}

// ---------------------------------------------------------------------------
__device__ __forceinline__ float edge_val(fvec4 p0, fvec4 p1, fvec4 p2, fvec4 p3) {
    const float a1x = p1.x - p0.x, a1y = p1.y - p0.y, a1z = p1.z - p0.z;
    const float a1l2 = a1x * a1x + a1y * a1y + a1z * a1z;
    const float a1l1 = fsqrt_(a1l2 + FEPS);
    const float inv_a1l2 = frcp(a1l2 + FEPS);

    const float b1x = p2.x - p0.x, b1y = p2.y - p0.y, b1z = p2.z - p0.z;
    const float b1l2 = b1x * b1x + b1y * b1y + b1z * b1z;
    const float b1l1 = fsqrt_(b1l2 + FEPS);
    const float ab1 = a1x * b1x + a1y * b1y + a1z * b1z;
    const float cos1 = ab1 * frcp(a1l1 * b1l1 + FEPS);
    const float sin1 = fsqrt_(1.0f - cos1 * cos1 + FEPS);
    const float f1 = ab1 * inv_a1l2;
    const float cb1x = b1x - a1x * f1, cb1y = b1y - a1y * f1, cb1z = b1z - a1z * f1;
    const float l1 = b1l1 * sin1;

    const float b2x = p3.x - p0.x, b2y = p3.y - p0.y, b2z = p3.z - p0.z;
    const float b2l2 = b2x * b2x + b2y * b2y + b2z * b2z;
    const float b2l1 = fsqrt_(b2l2 + FEPS);
    const float ab2 = a1x * b2x + a1y * b2y + a1z * b2z;
    const float cos2 = ab2 * frcp(a1l1 * b2l1 + FEPS);
    const float sin2 = fsqrt_(1.0f - cos2 * cos2 + FEPS);
    const float f2 = ab2 * inv_a1l2;
    const float cb2x = b2x - a1x * f2, cb2y = b2y - a1y * f2, cb2z = b2z - a1z * f2;
    const float l2 = b2l1 * sin2;

    const float cosd = (cb1x * cb2x + cb1y * cb2y + cb1z * cb2z) * frcp(l1 * l2 + FEPS);
    const float t = cosd + 1.0f;
    return t * t;
}

// ---------------------------------------------------------------------------
// Mega-kernel: one block = (2-row tile, batch).
//  - Stages v (with 1-row halo) into float4-PADDED LDS (each point = one
//    aligned 16B slot -> single ds_read_b128 per neighbor in the loss phase).
//  - View-stores (verts x4, tex x4) are fused into the staging loop and
//    issued straight from registers (no second LDS-read pass).
//  - Loss phase register-caches the 8-point neighborhood: 9 ds_read_b128
//    per vertex instead of 57 scalar ds_read_b32.
__global__ __launch_bounds__(256, 4) void mesh_fused_kernel(
    const float* __restrict__ disp, const float* __restrict__ center,
    const float* __restrict__ tex, const float* __restrict__ tv,
    float* __restrict__ out)
{
    // +1 slot pad: unconditional SE load at (lr+1=3, c+1=512) touches index
    // LDS_ROWS*NGRID; value is garbage but guarded off.
    __shared__ fvec4 vsp[LDS_ROWS * NGRID + 1];
    float* __restrict__ vs_f = (float*)vsp;

    const int tid = threadIdx.x;
    const int b = blockIdx.y;
    const int R0 = blockIdx.x * TR;

    const float c0 = tanhf(center[b * 3 + 0]);
    const float c1 = tanhf(center[b * 3 + 1]);
    const float c2 = tanhf(center[b * 3 + 2]);
    const float carr[3] = {c0, c1, c2};

    // ---- Stage v for rows [R0-1, R0+TR] into padded LDS, fused with the
    //      view-stores for owned rows ----
    {
        const fvec4* __restrict__ tv4 = (const fvec4*)tv;
        const fvec4* __restrict__ d4p = (const fvec4*)(disp + (size_t)b * NVF3);
        const fvec4* __restrict__ t4p = (const fvec4*)(tex + (size_t)b * NVF3);
        fvec4* __restrict__ out4 = (fvec4*)out;
        const size_t blk4 = NVF3 / 4;                       // 196608
        const int start4 = (R0 - 1) * (ROWF / 4);           // may be negative (tile 0)
#pragma unroll
        for (int ss = 0; ss < LDSF4 / 256; ++ss) {          // 6 iters
            const int q = ss * 256 + tid;                   // tile-local float4 idx
            const int g4 = start4 + q;                      // global float4 idx
            const int rowq = q / (ROWF / 4);                // 0..3 tile-local row
            if (g4 >= 0 && g4 < (int)(NVF3 / 4)) {
                const fvec4 t = tv4[g4];
                const fvec4 d = d4p[g4];
                fvec4 vr;
                int comp = q % 3;   // (4*q)%3 == q%3  (start4 % 3 == 0)
#pragma unroll
                for (int l = 0; l < 4; ++l) {
                    const float tvl = t[l];
                    const float s = fabsf(tvl);
                    const float sgn = (tvl > 0.0f) ? 1.0f : -1.0f;
                    // sigma = sigmoid(log(s/(1-s)) + d) = s / (s + (1-s)*exp(-d))
                    const float e = __expf(-d[l]);
                    const float sigma = s * frcp(fmaf(1.0f - s, e, s));
                    // v = relu(v0)(1-c) - relu(-v0)(1+c) + c == sigma*(sgn-c)+c
                    const float c = carr[comp];
                    vr[l] = fmaf(sigma, sgn - c, c);
                    comp = (comp == 2) ? 0 : comp + 1;
                }
                // Padded LDS writes: float fidx = 4q+l -> point fidx/3, comp fidx%3.
                // q = 3k+cc  =>  first point = 4k+cc, first comp = cc.
                {
                    const int k = q / 3;
                    const int cc = q - 3 * k;
                    int point = 4 * k + cc;
                    int comp2 = cc;
#pragma unroll
                    for (int l = 0; l < 4; ++l) {
                        vs_f[point * 4 + comp2] = vr[l];
                        comp2++;
                        if (comp2 == 3) { comp2 = 0; point++; }
                    }
                }
                // Fused view-stores for owned rows (global rows R0..R0+TR-1)
                if (rowq >= 1 && rowq <= TR) {
                    const fvec4 tx = __builtin_nontemporal_load(&t4p[g4]);
#pragma unroll
                    for (int view = 0; view < NVIEWS; ++view) {
                        const size_t base = (size_t)(b * NVIEWS + view) * blk4;
                        __builtin_nontemporal_store(vr, &out4[base + g4]);
                        __builtin_nontemporal_store(tx, &out4[(VERTS_FLOATS / 4) + base + g4]);
                    }
                }
            }
        }
    }
    __syncthreads();

    // ---- Lap + flat losses for owned rows: register-cached 8-neighborhood ----
    float lap_sum = 0.0f, flat_sum = 0.0f;
#pragma unroll 1
    for (int it = 0; it < TR * NGRID / 256; ++it) {
        const int idx = it * 256 + tid;
        const int r_off = idx >> 9;            // 0..TR-1
        const int c = idx & (NGRID - 1);
        const int gr = R0 + r_off;             // global row
        const int lr = r_off + 1;              // LDS row
        const int base = lr * NGRID + c;

        // 9 aligned ds_read_b128 loads; out-of-range neighbors load garbage
        // (in-bounds LDS memory) that the guards below never use.
        const fvec4 C  = vsp[base];
        const fvec4 Nn = vsp[base - NGRID];
        const fvec4 S  = vsp[base + NGRID];
        const fvec4 W  = vsp[base - 1];
        const fvec4 E  = vsp[base + 1];
        const fvec4 NE = vsp[base - NGRID + 1];
        const fvec4 SW = vsp[base + NGRID - 1];
        const fvec4 SE = vsp[base + NGRID + 1];

        // Laplacian (6-neighborhood of the unique-edge graph)
        {
            float sx = 0.f, sy = 0.f, sz = 0.f;
            int deg = 0;
            if (gr > 0)               { sx += Nn.x; sy += Nn.y; sz += Nn.z; deg++; }
            if (gr < NGRID - 1)       { sx += S.x;  sy += S.y;  sz += S.z;  deg++; }
            if (c > 0)                { sx += W.x;  sy += W.y;  sz += W.z;  deg++; }
            if (c < NGRID - 1)        { sx += E.x;  sy += E.y;  sz += E.z;  deg++; }
            if (gr > 0 && c < NGRID - 1)      { sx += NE.x; sy += NE.y; sz += NE.z; deg++; }
            if (gr < NGRID - 1 && c > 0)      { sx += SW.x; sy += SW.y; sz += SW.z; deg++; }
            const float id = frcp((float)deg);
            const float lx = C.x - sx * id;
            const float ly = C.y - sy * id;
            const float lz = C.z - sz * id;
            lap_sum += lx * lx + ly * ly + lz * lz;
        }

        // Flat loss: up to 3 structural edges anchored at (gr, c)
        if (gr < NGRID - 1 && c < NGRID - 1) {
            flat_sum += edge_val(E, S, C, SE);
        }
        if (gr >= 1 && gr < NGRID - 1 && c < NGRID - 1) {
            flat_sum += edge_val(C, E, S, NE);
        }
        if (gr < NGRID - 1 && c >= 1 && c < NGRID - 1) {
            flat_sum += edge_val(C, S, E, SW);
        }
    }

    // ---- Block reduction (two values), one atomic pair per block ----
#pragma unroll
    for (int off = 32; off > 0; off >>= 1) {
        lap_sum  += __shfl_down(lap_sum, off, 64);
        flat_sum += __shfl_down(flat_sum, off, 64);
    }
    __shared__ float red[8];
    const int lane = tid & 63;
    const int wid = tid >> 6;
    if (lane == 0) { red[wid] = lap_sum; red[4 + wid] = flat_sum; }
    __syncthreads();
    if (tid == 0) {
        const float ls = red[0] + red[1] + red[2] + red[3];
        const float fs = red[4] + red[5] + red[6] + red[7];
        atomicAdd(&out[LAP_OFF],  ls * (1.0f / NB));
        atomicAdd(&out[FLAT_OFF], fs * (1.0f / NB));
    }
}

// ---------------------------------------------------------------------------
extern "C" void kernel_launch(void* const* d_in, const int* in_sizes, int n_in,
                              void* d_out, int out_size, void* d_ws, size_t ws_size,
                              hipStream_t stream)
{
    const float* disp   = (const float*)d_in[0];
    const float* center = (const float*)d_in[1];
    const float* tex    = (const float*)d_in[2];
    const float* tv     = (const float*)d_in[3];
    float* out = (float*)d_out;

    init_losses<<<1, 64, 0, stream>>>(out);
    mesh_fused_kernel<<<dim3(NGRID / TR, NB), 256, 0, stream>>>(disp, center, tex, tv, out);
}